// Round 1
// baseline (2758.383 us; speedup 1.0000x reference)
//
#include <hip/hip_runtime.h>
#include <math.h>

#define N_NODES 16384
#define N_EDGES 262144
#define TOW 5
#define FI 75            // F_IN
#define FO 15            // F_OUT
#define DE 50
#define NL 4
#define NG 256
#define HW_PER_NODE (2*TOW*FI)   // 750: [hWi(375) | hWj(375)]

static __device__ float g_hA[N_NODES*FI];
static __device__ float g_hB[N_NODES*FI];
static __device__ float g_hW[N_NODES*HW_PER_NODE];
static __device__ float g_ec[4*TOW*FI];
static __device__ int   g_deg[N_NODES];
static __device__ int   g_rowstart[N_NODES+1];
static __device__ int   g_cursor[N_NODES];
static __device__ int   g_edge[N_EDGES];
static __device__ float g_mu[FI];
static __device__ float g_rsig[FI];
static __device__ float g_pool[NG*FI];

__global__ void k_embed(const int* __restrict__ x, const float* __restrict__ node_emb) {
    int i = blockIdx.x * blockDim.x + threadIdx.x;
    if (i < N_NODES*FI) {
        int n = i / FI, f = i % FI;
        g_hA[i] = node_emb[x[n]*FI + f];
    }
}

__global__ void k_zerodeg() {
    int i = blockIdx.x * blockDim.x + threadIdx.x;
    if (i < N_NODES) g_deg[i] = 0;
}

__global__ void k_hist(const int* __restrict__ dst) {
    int e = blockIdx.x * blockDim.x + threadIdx.x;
    if (e < N_EDGES) atomicAdd(&g_deg[dst[e]], 1);
}

// single-block exclusive scan of g_deg (16384) -> g_rowstart, g_cursor
__global__ void k_scan() {
    __shared__ int part[1024];
    int t = threadIdx.x;
    int base = t * 16;
    int loc[16];
    int s = 0;
    #pragma unroll
    for (int i = 0; i < 16; i++) { loc[i] = s; s += g_deg[base + i]; }
    part[t] = s;
    __syncthreads();
    for (int off = 1; off < 1024; off <<= 1) {
        int v = 0;
        if (t >= off) v = part[t - off];
        __syncthreads();
        if (t >= off) part[t] += v;
        __syncthreads();
    }
    int excl = (t == 0) ? 0 : part[t - 1];
    #pragma unroll
    for (int i = 0; i < 16; i++) {
        g_rowstart[base + i] = excl + loc[i];
        g_cursor[base + i]   = excl + loc[i];
    }
    if (t == 1023) g_rowstart[N_NODES] = part[1023];
}

__global__ void k_scatter(const int* __restrict__ src, const int* __restrict__ dst,
                          const int* __restrict__ attr) {
    int e = blockIdx.x * blockDim.x + threadIdx.x;
    if (e < N_EDGES) {
        int d = dst[e];
        int pos = atomicAdd(&g_cursor[d], 1);
        g_edge[pos] = src[e] | (attr[e] << 16);
    }
}

// per-layer: edge contribution table ec[a][t][g] = (edge_emb[a]@eew + eeb) @ We[t] + pb[t]
__global__ void k_ec(const float* __restrict__ edge_emb, const float* __restrict__ eew,
                     const float* __restrict__ eeb, const float* __restrict__ pw,
                     const float* __restrict__ pb) {
    __shared__ float e_enc[4*FI];
    int t = threadIdx.x;
    if (t < 4*FI) {
        int a = t / FI, f = t % FI;
        float s = eeb[f];
        for (int d = 0; d < DE; d++) s += edge_emb[a*DE + d] * eew[d*FI + f];
        e_enc[t] = s;
    }
    __syncthreads();
    for (int o = t; o < 4*TOW*FI; o += blockDim.x) {
        int a = o / (TOW*FI);
        int r = o % (TOW*FI);
        int tw = r / FI, g = r % FI;
        float s = pb[tw*FI + g];
        const float* W = pw + (tw*(3*FI) + 2*FI)*FI + g;   // We[t][f][g]
        for (int f = 0; f < FI; f++) s += e_enc[a*FI + f] * W[f*FI];
        g_ec[o] = s;
    }
}

// node transform: hW[n][0:375]=h[n]@Wi (per tower), hW[n][375:750]=h[n]@Wj
// 8 nodes per block for weight reuse.
#define NPB 8
__global__ void k_hw(const float* __restrict__ pw) {
    __shared__ float hsh[NPB*FI];
    int n0 = blockIdx.x * NPB;
    int tid = threadIdx.x;
    for (int i = tid; i < NPB*FI; i += blockDim.x)
        hsh[i] = g_hA[(n0 + i/FI)*FI + (i % FI)];
    __syncthreads();
    for (int o = tid; o < HW_PER_NODE; o += blockDim.x) {
        int half = o / (TOW*FI);
        int r = o % (TOW*FI);
        int tw = r / FI, g = r % FI;
        const float* W = pw + (tw*(3*FI) + half*FI)*FI + g;
        float acc[NPB];
        #pragma unroll
        for (int nn = 0; nn < NPB; nn++) acc[nn] = 0.f;
        for (int f = 0; f < FI; f++) {
            float w = W[f*FI];
            #pragma unroll
            for (int nn = 0; nn < NPB; nn++) acc[nn] += hsh[nn*FI + f] * w;
        }
        #pragma unroll
        for (int nn = 0; nn < NPB; nn++) g_hW[(n0+nn)*HW_PER_NODE + o] = acc[nn];
    }
}

// per-node aggregation + post-GEMM + lin, one block per node
__global__ void k_agg(const float* __restrict__ qw, const float* __restrict__ qb,
                      const float* __restrict__ lw, const float* __restrict__ lb) {
    __shared__ float agg[TOW*300];
    __shared__ float post[TOW*FO];
    __shared__ float part[375];
    int n = blockIdx.x;
    int tid = threadIdx.x;
    int e0 = g_rowstart[n], e1 = g_rowstart[n+1];
    int cnt = e1 - e0;

    if (tid < TOW*FI) {
        float hwi = g_hW[n*HW_PER_NODE + tid];
        float s = 0.f, s2 = 0.f, mn = 1e30f, mx = -1e30f;
        for (int e = e0; e < e1; e++) {
            int pk = g_edge[e];
            int sn = pk & 0xFFFF;
            int a  = pk >> 16;
            float m = hwi + g_hW[sn*HW_PER_NODE + TOW*FI + tid] + g_ec[a*TOW*FI + tid];
            s += m; s2 += m*m;
            mn = fminf(mn, m); mx = fmaxf(mx, m);
        }
        float deg = (cnt > 0) ? (float)cnt : 1.0f;
        float mean  = s / deg;
        float mean2 = s2 / deg;
        float var = mean2 - mean*mean;
        if (var < 0.f) var = 0.f;
        float sd = sqrtf(var + 1e-5f);
        if (cnt == 0) { mn = 0.f; mx = 0.f; }
        int tw = tid / FI, g = tid % FI;
        agg[tw*300 +        g] = mean;
        agg[tw*300 +  FI  + g] = mn;
        agg[tw*300 + 2*FI + g] = mx;
        agg[tw*300 + 3*FI + g] = sd;
    }
    __syncthreads();

    float degf = (cnt > 0) ? (float)cnt : 1.0f;
    float amp  = logf(degf + 1.0f) * (1.0f/2.8332133440562162f);
    float iamp = 1.0f / amp;

    // post[o] for o = tw*15+g : dot(agg[tw][0:300], qw_eff) ; split over 5 partials
    if (tid < 375) {
        int o = tid % (TOW*FO);       // 0..74
        int p = tid / (TOW*FO);       // 0..4
        int tw = o / FO, g = o % FO;
        const float* q = qw + tw*900*FO + g;
        float s = 0.f;
        int f0 = p*60, f1 = f0 + 60;
        for (int f = f0; f < f1; f++) {
            float av = agg[tw*300 + f];
            s += av * (q[f*FO] + amp*q[(300+f)*FO] + iamp*q[(600+f)*FO]);
        }
        part[p*(TOW*FO) + o] = s;
    }
    __syncthreads();
    if (tid < TOW*FO) {
        float s = qb[tid];
        #pragma unroll
        for (int p = 0; p < 5; p++) s += part[p*(TOW*FO) + tid];
        post[tid] = s;
    }
    __syncthreads();
    // lin: out[g2] = post @ lw + lb ; 5 partials of 15 each
    if (tid < 375) {
        int g2 = tid % (TOW*FO);
        int p  = tid / (TOW*FO);
        float s = 0.f;
        int f0 = p*FO, f1 = f0 + FO;
        for (int f = f0; f < f1; f++) s += post[f] * lw[f*(TOW*FO) + g2];
        part[p*(TOW*FO) + g2] = s;
    }
    __syncthreads();
    if (tid < TOW*FO) {
        float s = lb[tid];
        #pragma unroll
        for (int p = 0; p < 5; p++) s += part[p*(TOW*FO) + tid];
        g_hB[n*(TOW*FO) + tid] = s;
    }
}

// BN stats: one block per channel, double accumulation
__global__ void k_bnstat() {
    int c = blockIdx.x;
    int t = threadIdx.x;
    double s = 0.0, s2 = 0.0;
    for (int n = t; n < N_NODES; n += 256) {
        float v = g_hB[n*FI + c];
        s += v; s2 += (double)v * v;
    }
    __shared__ double ps[256], ps2[256];
    ps[t] = s; ps2[t] = s2;
    __syncthreads();
    for (int off = 128; off > 0; off >>= 1) {
        if (t < off) { ps[t] += ps[t+off]; ps2[t] += ps2[t+off]; }
        __syncthreads();
    }
    if (t == 0) {
        double mu = ps[0] / N_NODES;
        double var = ps2[0] / N_NODES - mu*mu;
        if (var < 0.0) var = 0.0;
        g_mu[c]   = (float)mu;
        g_rsig[c] = (float)(1.0 / sqrt(var + 1e-5));
    }
}

__global__ void k_bnapply(const float* __restrict__ gamma, const float* __restrict__ beta) {
    int i = blockIdx.x * blockDim.x + threadIdx.x;
    if (i < N_NODES*FI) {
        int c = i % FI;
        float v = (g_hB[i] - g_mu[c]) * g_rsig[c] * gamma[c] + beta[c];
        g_hA[i] = v > 0.f ? v : 0.f;
    }
}

__global__ void k_poolzero() {
    int i = blockIdx.x * blockDim.x + threadIdx.x;
    if (i < NG*FI) g_pool[i] = 0.f;
}

__global__ void k_pool(const int* __restrict__ batch) {
    int i = blockIdx.x * blockDim.x + threadIdx.x;
    if (i < N_NODES*FI) {
        int n = i / FI, c = i % FI;
        atomicAdd(&g_pool[batch[n]*FI + c], g_hA[i]);
    }
}

__global__ void k_mlp(const float* __restrict__ w1, const float* __restrict__ b1,
                      const float* __restrict__ w2, const float* __restrict__ b2,
                      const float* __restrict__ w3, const float* __restrict__ b3,
                      float* __restrict__ out) {
    __shared__ float gin[FI], h1[50], h2[25];
    int gi = blockIdx.x;
    int t = threadIdx.x;
    if (t < FI) gin[t] = g_pool[gi*FI + t];
    __syncthreads();
    if (t < 50) {
        float s = b1[t];
        for (int f = 0; f < FI; f++) s += gin[f] * w1[f*50 + t];
        h1[t] = s > 0.f ? s : 0.f;
    }
    __syncthreads();
    if (t < 25) {
        float s = b2[t];
        for (int f = 0; f < 50; f++) s += h1[f] * w2[f*25 + t];
        h2[t] = s > 0.f ? s : 0.f;
    }
    __syncthreads();
    if (t == 0) {
        float s = b3[0];
        for (int f = 0; f < 25; f++) s += h2[f] * w3[f];
        out[gi] = s;
    }
}

extern "C" void kernel_launch(void* const* d_in, const int* in_sizes, int n_in,
                              void* d_out, int out_size, void* d_ws, size_t ws_size,
                              hipStream_t stream) {
    const int*   x          = (const int*)  d_in[0];
    const int*   edge_index = (const int*)  d_in[1];
    const int*   edge_attr  = (const int*)  d_in[2];
    const int*   batch      = (const int*)  d_in[3];
    const float* node_emb   = (const float*)d_in[4];
    const float* edge_emb   = (const float*)d_in[5];
    const float* edge_enc_w = (const float*)d_in[6];
    const float* edge_enc_b = (const float*)d_in[7];
    const float* pre_w      = (const float*)d_in[8];
    const float* pre_b      = (const float*)d_in[9];
    const float* post_w     = (const float*)d_in[10];
    const float* post_b     = (const float*)d_in[11];
    const float* lin_w      = (const float*)d_in[12];
    const float* lin_b      = (const float*)d_in[13];
    const float* bn_gamma   = (const float*)d_in[14];
    const float* bn_beta    = (const float*)d_in[15];
    const float* mlp_w1     = (const float*)d_in[16];
    const float* mlp_b1     = (const float*)d_in[17];
    const float* mlp_w2     = (const float*)d_in[18];
    const float* mlp_b2     = (const float*)d_in[19];
    const float* mlp_w3     = (const float*)d_in[20];
    const float* mlp_b3     = (const float*)d_in[21];
    float* out = (float*)d_out;

    const int* src = edge_index;
    const int* dst = edge_index + N_EDGES;

    k_embed<<<(N_NODES*FI + 255)/256, 256, 0, stream>>>(x, node_emb);
    k_zerodeg<<<(N_NODES + 255)/256, 256, 0, stream>>>();
    k_hist<<<(N_EDGES + 255)/256, 256, 0, stream>>>(dst);
    k_scan<<<1, 1024, 0, stream>>>();
    k_scatter<<<(N_EDGES + 255)/256, 256, 0, stream>>>(src, dst, edge_attr);

    for (int l = 0; l < NL; l++) {
        const float* eew = edge_enc_w + l*DE*FI;
        const float* eeb = edge_enc_b + l*FI;
        const float* pw  = pre_w  + l*TOW*(3*FI)*FI;
        const float* pb  = pre_b  + l*TOW*FI;
        const float* qw  = post_w + l*TOW*900*FO;
        const float* qb  = post_b + l*TOW*FO;
        const float* lw  = lin_w  + l*(TOW*FO)*(TOW*FO);
        const float* lb  = lin_b  + l*TOW*FO;
        const float* gam = bn_gamma + l*FI;
        const float* bet = bn_beta  + l*FI;

        k_ec<<<1, 512, 0, stream>>>(edge_emb, eew, eeb, pw, pb);
        k_hw<<<N_NODES/NPB, 256, 0, stream>>>(pw);
        k_agg<<<N_NODES, 384, 0, stream>>>(qw, qb, lw, lb);
        k_bnstat<<<FI, 256, 0, stream>>>();
        k_bnapply<<<(N_NODES*FI + 255)/256, 256, 0, stream>>>(gam, bet);
    }

    k_poolzero<<<(NG*FI + 255)/256, 256, 0, stream>>>();
    k_pool<<<(N_NODES*FI + 255)/256, 256, 0, stream>>>(batch);
    k_mlp<<<NG, 128, 0, stream>>>(mlp_w1, mlp_b1, mlp_w2, mlp_b2, mlp_w3, mlp_b3, out);
}

// Round 2
// 1319.387 us; speedup vs baseline: 2.0907x; 2.0907x over previous
//
#include <hip/hip_runtime.h>
#include <math.h>

#define N_NODES 16384
#define N_EDGES 262144
#define TOW 5
#define FI 75            // F_IN
#define FO 15            // F_OUT
#define DE 50
#define NL 4
#define NG 256
#define HWP 752          // padded node-transform stride: [hWi 0..374][pad][hWj 376..750][pad]
#define NQ 94            // channel quads (376/4)
#define NPN 4            // nodes per k_agg block
#define ECAP 256         // edge staging chunk

static __device__ float g_hA[N_NODES*FI];
static __device__ float g_hB[N_NODES*FI];
static __device__ float g_hW[N_NODES*HWP];
static __device__ float g_ec[4*376];
static __device__ int   g_deg[N_NODES];
static __device__ int   g_rowstart[N_NODES+1];
static __device__ int   g_cursor[N_NODES];
static __device__ int   g_edge[N_EDGES];
static __device__ float g_mu[FI];
static __device__ float g_rsig[FI];
static __device__ float g_pool[NG*FI];

__global__ void k_embed(const int* __restrict__ x, const float* __restrict__ node_emb) {
    int i = blockIdx.x * blockDim.x + threadIdx.x;
    if (i < N_NODES*FI) {
        int n = i / FI, f = i % FI;
        g_hA[i] = node_emb[x[n]*FI + f];
    }
}

__global__ void k_zerodeg() {
    int i = blockIdx.x * blockDim.x + threadIdx.x;
    if (i < N_NODES) g_deg[i] = 0;
}

__global__ void k_hist(const int* __restrict__ dst) {
    int e = blockIdx.x * blockDim.x + threadIdx.x;
    if (e < N_EDGES) atomicAdd(&g_deg[dst[e]], 1);
}

// single-block exclusive scan of g_deg (16384) -> g_rowstart, g_cursor
__global__ void k_scan() {
    __shared__ int part[1024];
    int t = threadIdx.x;
    int base = t * 16;
    int loc[16];
    int s = 0;
    #pragma unroll
    for (int i = 0; i < 16; i++) { loc[i] = s; s += g_deg[base + i]; }
    part[t] = s;
    __syncthreads();
    for (int off = 1; off < 1024; off <<= 1) {
        int v = 0;
        if (t >= off) v = part[t - off];
        __syncthreads();
        if (t >= off) part[t] += v;
        __syncthreads();
    }
    int excl = (t == 0) ? 0 : part[t - 1];
    #pragma unroll
    for (int i = 0; i < 16; i++) {
        g_rowstart[base + i] = excl + loc[i];
        g_cursor[base + i]   = excl + loc[i];
    }
    if (t == 1023) g_rowstart[N_NODES] = part[1023];
}

__global__ void k_scatter(const int* __restrict__ src, const int* __restrict__ dst,
                          const int* __restrict__ attr) {
    int e = blockIdx.x * blockDim.x + threadIdx.x;
    if (e < N_EDGES) {
        int d = dst[e];
        int pos = atomicAdd(&g_cursor[d], 1);
        g_edge[pos] = src[e] | (attr[e] << 16);
    }
}

// per-layer: edge contribution table ec[a][c] (padded to 376 channels)
__global__ void k_ec(const float* __restrict__ edge_emb, const float* __restrict__ eew,
                     const float* __restrict__ eeb, const float* __restrict__ pw,
                     const float* __restrict__ pb) {
    __shared__ float e_enc[4*FI];
    int t = threadIdx.x;
    if (t < 4*FI) {
        int a = t / FI, f = t % FI;
        float s = eeb[f];
        for (int d = 0; d < DE; d++) s += edge_emb[a*DE + d] * eew[d*FI + f];
        e_enc[t] = s;
    }
    __syncthreads();
    for (int o = t; o < 4*376; o += blockDim.x) {
        int a = o / 376;
        int r = o % 376;
        float s = 0.f;
        if (r < TOW*FI) {
            int tw = r / FI, g = r % FI;
            s = pb[tw*FI + g];
            const float* W = pw + (tw*(3*FI) + 2*FI)*FI + g;   // We[t][f][g]
            for (int f = 0; f < FI; f++) s += e_enc[a*FI + f] * W[f*FI];
        }
        g_ec[o] = s;
    }
}

// node transform: hW[n][0:375]=h[n]@Wi (per tower), hW[n][376:751]=h[n]@Wj
#define NPB 8
__global__ void k_hw(const float* __restrict__ pw) {
    __shared__ float hsh[NPB*FI];
    int n0 = blockIdx.x * NPB;
    int tid = threadIdx.x;
    for (int i = tid; i < NPB*FI; i += blockDim.x)
        hsh[i] = g_hA[(n0 + i/FI)*FI + (i % FI)];
    __syncthreads();
    for (int o = tid; o < 2*TOW*FI; o += blockDim.x) {
        int half = o / (TOW*FI);
        int r = o % (TOW*FI);
        int tw = r / FI, g = r % FI;
        const float* W = pw + (tw*(3*FI) + half*FI)*FI + g;
        float acc[NPB];
        #pragma unroll
        for (int nn = 0; nn < NPB; nn++) acc[nn] = 0.f;
        for (int f = 0; f < FI; f++) {
            float w = W[f*FI];
            #pragma unroll
            for (int nn = 0; nn < NPB; nn++) acc[nn] += hsh[nn*FI + f] * w;
        }
        #pragma unroll
        for (int nn = 0; nn < NPB; nn++)
            g_hW[(n0+nn)*HWP + half*376 + r] = acc[nn];
    }
}

// per-node aggregation + post-GEMM + lin: NPN nodes per block, 384 threads.
// Edge phase: 94 channel-quads (float4) x 4 edge-lanes.
__global__ __launch_bounds__(384) void
k_agg(const float* __restrict__ qw, const float* __restrict__ qb,
      const float* __restrict__ lw, const float* __restrict__ lb) {
    __shared__ float  agg[NPN*1500];       // [nn][tw*300 + kind*75 + f]
    __shared__ float4 red[564];            // 3*188 reduce buf; reused as part4[375]
    __shared__ int    es[ECAP];
    __shared__ float  post[NPN*FI];
    __shared__ float  s_amp[NPN], s_iamp[NPN];

    int tid = threadIdx.x;
    int n0 = blockIdx.x * NPN;
    int q  = tid % NQ;         // 0..93
    int el = tid / NQ;         // 0..3 for active
    bool act = tid < 4*NQ;     // 376 active

    for (int nn = 0; nn < NPN; nn++) {
        int n  = n0 + nn;
        int e0 = g_rowstart[n], e1 = g_rowstart[n+1];
        int cnt = e1 - e0;

        float s0=0.f,s1=0.f,s2=0.f,s3=0.f;
        float t0=0.f,t1=0.f,t2=0.f,t3=0.f;
        float mn0=1e30f,mn1=1e30f,mn2=1e30f,mn3=1e30f;
        float mx0=-1e30f,mx1=-1e30f,mx2=-1e30f,mx3=-1e30f;
        float4 hwi = {0,0,0,0};
        if (act) hwi = *(const float4*)&g_hW[n*HWP + 4*q];

        for (int base = e0; base < e1; base += ECAP) {
            int mcnt = min(ECAP, e1 - base);
            __syncthreads();
            for (int i = tid; i < mcnt; i += 384) es[i] = g_edge[base + i];
            __syncthreads();
            if (act) {
                for (int i = el; i < mcnt; i += 4) {
                    int pk = es[i];
                    int sn = pk & 0xFFFF;
                    int a  = pk >> 16;
                    float4 hj = *(const float4*)&g_hW[sn*HWP + 376 + 4*q];
                    float4 ec = *(const float4*)&g_ec[a*376 + 4*q];
                    float m0 = hwi.x + hj.x + ec.x;
                    float m1 = hwi.y + hj.y + ec.y;
                    float m2 = hwi.z + hj.z + ec.z;
                    float m3 = hwi.w + hj.w + ec.w;
                    s0 += m0; s1 += m1; s2 += m2; s3 += m3;
                    t0 += m0*m0; t1 += m1*m1; t2 += m2*m2; t3 += m3*m3;
                    mn0 = fminf(mn0,m0); mn1 = fminf(mn1,m1);
                    mn2 = fminf(mn2,m2); mn3 = fminf(mn3,m3);
                    mx0 = fmaxf(mx0,m0); mx1 = fmaxf(mx1,m1);
                    mx2 = fmaxf(mx2,m2); mx3 = fmaxf(mx3,m3);
                }
            }
        }
        // cross-el reduce, pass A: sum & sum2
        __syncthreads();
        if (act && el > 0) {
            red[(el-1)*188 + 2*q]     = make_float4(s0,s1,s2,s3);
            red[(el-1)*188 + 2*q + 1] = make_float4(t0,t1,t2,t3);
        }
        __syncthreads();
        if (act && el == 0) {
            #pragma unroll
            for (int r = 0; r < 3; r++) {
                float4 a4 = red[r*188 + 2*q];
                float4 b4 = red[r*188 + 2*q + 1];
                s0 += a4.x; s1 += a4.y; s2 += a4.z; s3 += a4.w;
                t0 += b4.x; t1 += b4.y; t2 += b4.z; t3 += b4.w;
            }
        }
        __syncthreads();
        if (act && el > 0) {
            red[(el-1)*188 + 2*q]     = make_float4(mn0,mn1,mn2,mn3);
            red[(el-1)*188 + 2*q + 1] = make_float4(mx0,mx1,mx2,mx3);
        }
        __syncthreads();
        if (act && el == 0) {
            #pragma unroll
            for (int r = 0; r < 3; r++) {
                float4 a4 = red[r*188 + 2*q];
                float4 b4 = red[r*188 + 2*q + 1];
                mn0 = fminf(mn0,a4.x); mn1 = fminf(mn1,a4.y);
                mn2 = fminf(mn2,a4.z); mn3 = fminf(mn3,a4.w);
                mx0 = fmaxf(mx0,b4.x); mx1 = fmaxf(mx1,b4.y);
                mx2 = fmaxf(mx2,b4.z); mx3 = fmaxf(mx3,b4.w);
            }
            float deg = (cnt > 0) ? (float)cnt : 1.0f;
            float inv = 1.0f / deg;
            float sv[4]  = {s0,s1,s2,s3};
            float tv[4]  = {t0,t1,t2,t3};
            float mnv[4] = {mn0,mn1,mn2,mn3};
            float mxv[4] = {mx0,mx1,mx2,mx3};
            #pragma unroll
            for (int j = 0; j < 4; j++) {
                int c = 4*q + j;
                if (c < TOW*FI) {
                    float mean  = sv[j] * inv;
                    float mean2 = tv[j] * inv;
                    float var = mean2 - mean*mean;
                    if (var < 0.f) var = 0.f;
                    float sd = sqrtf(var + 1e-5f);
                    float vmn = (cnt > 0) ? mnv[j] : 0.f;
                    float vmx = (cnt > 0) ? mxv[j] : 0.f;
                    int tw = c / FI, f = c % FI;
                    int b2 = nn*1500 + tw*300;
                    agg[b2 +        f] = mean;
                    agg[b2 +  FI  + f] = vmn;
                    agg[b2 + 2*FI + f] = vmx;
                    agg[b2 + 3*FI + f] = sd;
                }
            }
        }
        if (tid == 0) {
            float deg = (cnt > 0) ? (float)cnt : 1.0f;
            float amp = logf(deg + 1.0f) * (1.0f/2.8332133440562162f);
            s_amp[nn]  = amp;
            s_iamp[nn] = 1.0f/amp;
        }
    }
    __syncthreads();

    float amp[NPN], iamp[NPN];
    #pragma unroll
    for (int nn = 0; nn < NPN; nn++) { amp[nn] = s_amp[nn]; iamp[nn] = s_iamp[nn]; }

    float4* part4 = red;   // reuse (375 <= 564)

    // post: out[o] = dot(agg[tw][0:300], q0 + amp*q1 + iamp*q2), 5 partials x 60
    if (tid < 375) {
        int o = tid % (TOW*FO);
        int p = tid / (TOW*FO);
        int tw = o / FO, g = o % FO;
        const float* qp = qw + tw*900*FO + g;
        float sp[NPN] = {0.f,0.f,0.f,0.f};
        for (int f = p*60; f < p*60 + 60; f++) {
            float w0 = qp[f*FO];
            float w1 = qp[(300+f)*FO];
            float w2 = qp[(600+f)*FO];
            #pragma unroll
            for (int nn = 0; nn < NPN; nn++) {
                float av = agg[nn*1500 + tw*300 + f];
                sp[nn] += av * (w0 + amp[nn]*w1 + iamp[nn]*w2);
            }
        }
        part4[p*75 + o] = make_float4(sp[0],sp[1],sp[2],sp[3]);
    }
    __syncthreads();
    if (tid < TOW*FO) {
        float4 a = part4[tid];
        #pragma unroll
        for (int p = 1; p < 5; p++) {
            float4 b = part4[p*75 + tid];
            a.x += b.x; a.y += b.y; a.z += b.z; a.w += b.w;
        }
        float qbv = qb[tid];
        post[0*75 + tid] = qbv + a.x;
        post[1*75 + tid] = qbv + a.y;
        post[2*75 + tid] = qbv + a.z;
        post[3*75 + tid] = qbv + a.w;
    }
    __syncthreads();
    // lin: 5 partials x 15
    if (tid < 375) {
        int o = tid % (TOW*FO);
        int p = tid / (TOW*FO);
        float sp[NPN] = {0.f,0.f,0.f,0.f};
        for (int f = p*FO; f < p*FO + FO; f++) {
            float w = lw[f*(TOW*FO) + o];
            #pragma unroll
            for (int nn = 0; nn < NPN; nn++) sp[nn] += post[nn*75 + f] * w;
        }
        part4[p*75 + o] = make_float4(sp[0],sp[1],sp[2],sp[3]);
    }
    __syncthreads();
    if (tid < TOW*FO) {
        float4 a = part4[tid];
        #pragma unroll
        for (int p = 1; p < 5; p++) {
            float4 b = part4[p*75 + tid];
            a.x += b.x; a.y += b.y; a.z += b.z; a.w += b.w;
        }
        float lbv = lb[tid];
        g_hB[(n0+0)*FI + tid] = lbv + a.x;
        g_hB[(n0+1)*FI + tid] = lbv + a.y;
        g_hB[(n0+2)*FI + tid] = lbv + a.z;
        g_hB[(n0+3)*FI + tid] = lbv + a.w;
    }
}

// BN stats: one block per channel
__global__ void k_bnstat() {
    int c = blockIdx.x;
    int t = threadIdx.x;
    double s = 0.0, s2 = 0.0;
    for (int n = t; n < N_NODES; n += 256) {
        float v = g_hB[n*FI + c];
        s += v; s2 += (double)v * v;
    }
    __shared__ double ps[256], ps2[256];
    ps[t] = s; ps2[t] = s2;
    __syncthreads();
    for (int off = 128; off > 0; off >>= 1) {
        if (t < off) { ps[t] += ps[t+off]; ps2[t] += ps2[t+off]; }
        __syncthreads();
    }
    if (t == 0) {
        double mu = ps[0] / N_NODES;
        double var = ps2[0] / N_NODES - mu*mu;
        if (var < 0.0) var = 0.0;
        g_mu[c]   = (float)mu;
        g_rsig[c] = (float)(1.0 / sqrt(var + 1e-5));
    }
}

__global__ void k_bnapply(const float* __restrict__ gamma, const float* __restrict__ beta) {
    int i = blockIdx.x * blockDim.x + threadIdx.x;
    if (i < N_NODES*FI) {
        int c = i % FI;
        float v = (g_hB[i] - g_mu[c]) * g_rsig[c] * gamma[c] + beta[c];
        g_hA[i] = v > 0.f ? v : 0.f;
    }
}

__global__ void k_poolzero() {
    int i = blockIdx.x * blockDim.x + threadIdx.x;
    if (i < NG*FI) g_pool[i] = 0.f;
}

__global__ void k_pool(const int* __restrict__ batch) {
    int i = blockIdx.x * blockDim.x + threadIdx.x;
    if (i < N_NODES*FI) {
        int n = i / FI, c = i % FI;
        atomicAdd(&g_pool[batch[n]*FI + c], g_hA[i]);
    }
}

__global__ void k_mlp(const float* __restrict__ w1, const float* __restrict__ b1,
                      const float* __restrict__ w2, const float* __restrict__ b2,
                      const float* __restrict__ w3, const float* __restrict__ b3,
                      float* __restrict__ out) {
    __shared__ float gin[FI], h1[50], h2[25];
    int gi = blockIdx.x;
    int t = threadIdx.x;
    if (t < FI) gin[t] = g_pool[gi*FI + t];
    __syncthreads();
    if (t < 50) {
        float s = b1[t];
        for (int f = 0; f < FI; f++) s += gin[f] * w1[f*50 + t];
        h1[t] = s > 0.f ? s : 0.f;
    }
    __syncthreads();
    if (t < 25) {
        float s = b2[t];
        for (int f = 0; f < 50; f++) s += h1[f] * w2[f*25 + t];
        h2[t] = s > 0.f ? s : 0.f;
    }
    __syncthreads();
    if (t == 0) {
        float s = b3[0];
        for (int f = 0; f < 25; f++) s += h2[f] * w3[f];
        out[gi] = s;
    }
}

extern "C" void kernel_launch(void* const* d_in, const int* in_sizes, int n_in,
                              void* d_out, int out_size, void* d_ws, size_t ws_size,
                              hipStream_t stream) {
    const int*   x          = (const int*)  d_in[0];
    const int*   edge_index = (const int*)  d_in[1];
    const int*   edge_attr  = (const int*)  d_in[2];
    const int*   batch      = (const int*)  d_in[3];
    const float* node_emb   = (const float*)d_in[4];
    const float* edge_emb   = (const float*)d_in[5];
    const float* edge_enc_w = (const float*)d_in[6];
    const float* edge_enc_b = (const float*)d_in[7];
    const float* pre_w      = (const float*)d_in[8];
    const float* pre_b      = (const float*)d_in[9];
    const float* post_w     = (const float*)d_in[10];
    const float* post_b     = (const float*)d_in[11];
    const float* lin_w      = (const float*)d_in[12];
    const float* lin_b      = (const float*)d_in[13];
    const float* bn_gamma   = (const float*)d_in[14];
    const float* bn_beta    = (const float*)d_in[15];
    const float* mlp_w1     = (const float*)d_in[16];
    const float* mlp_b1     = (const float*)d_in[17];
    const float* mlp_w2     = (const float*)d_in[18];
    const float* mlp_b2     = (const float*)d_in[19];
    const float* mlp_w3     = (const float*)d_in[20];
    const float* mlp_b3     = (const float*)d_in[21];
    float* out = (float*)d_out;

    const int* src = edge_index;
    const int* dst = edge_index + N_EDGES;

    k_embed<<<(N_NODES*FI + 255)/256, 256, 0, stream>>>(x, node_emb);
    k_zerodeg<<<(N_NODES + 255)/256, 256, 0, stream>>>();
    k_hist<<<(N_EDGES + 255)/256, 256, 0, stream>>>(dst);
    k_scan<<<1, 1024, 0, stream>>>();
    k_scatter<<<(N_EDGES + 255)/256, 256, 0, stream>>>(src, dst, edge_attr);

    for (int l = 0; l < NL; l++) {
        const float* eew = edge_enc_w + l*DE*FI;
        const float* eeb = edge_enc_b + l*FI;
        const float* pw  = pre_w  + l*TOW*(3*FI)*FI;
        const float* pb  = pre_b  + l*TOW*FI;
        const float* qw  = post_w + l*TOW*900*FO;
        const float* qb  = post_b + l*TOW*FO;
        const float* lw  = lin_w  + l*(TOW*FO)*(TOW*FO);
        const float* lb  = lin_b  + l*TOW*FO;
        const float* gam = bn_gamma + l*FI;
        const float* bet = bn_beta  + l*FI;

        k_ec<<<1, 512, 0, stream>>>(edge_emb, eew, eeb, pw, pb);
        k_hw<<<N_NODES/NPB, 256, 0, stream>>>(pw);
        k_agg<<<N_NODES/NPN, 384, 0, stream>>>(qw, qb, lw, lb);
        k_bnstat<<<FI, 256, 0, stream>>>();
        k_bnapply<<<(N_NODES*FI + 255)/256, 256, 0, stream>>>(gam, bet);
    }

    k_poolzero<<<(NG*FI + 255)/256, 256, 0, stream>>>();
    k_pool<<<(N_NODES*FI + 255)/256, 256, 0, stream>>>(batch);
    k_mlp<<<NG, 128, 0, stream>>>(mlp_w1, mlp_b1, mlp_w2, mlp_b2, mlp_w3, mlp_b3, out);
}